// Round 2
// baseline (36687.878 us; speedup 1.0000x reference)
//
#include <hip/hip_runtime.h>
#include <cstdint>

// ============================================================================
// EncoderLSTMReal: reverse LSTM (T=200,B=1024,H=512,IN=64) + 2 tanh-MLP heads.
// CONTRACT (established R0-R8):
//   - inputs fp32, dict order (R6 NaN kills bf16-input; R5 permutation test)
//   - OUTPUT FLOAT32 (R8 probe: a bf16-stride write at out[0] was invisible
//     to the readout => 4-byte elements; mu = out[0..32768), logvar next)
//   - engines R4(tiled) == R7(naive) function-identical (same 0.574 signature)
// Round-11 (R2 of this session): scalar-pipe weights.
//   R1 post-mortem: inner loop was LDS-BW-bound (10 KB LDS read / 64 FMA
//   instr = 160 B/instr; 38 us of 71 us). New layout: wave = one gate,
//   64 lanes = 64 rows, 16 cols/lane. Weight addresses are wave-uniform
//   (readfirstlane'd wave id) => compiler emits s_load into SGPRs; FMA takes
//   the weight as its one SGPR operand. LDS now carries ONLY activations:
//   1 ds_read_b128 per wave per k4 (16 B/FMA-instr, 10x less).
//   Tile: 64 rows x (4 gates x 16 jj); grid 512 = 16 mtile x 32 ntile.
//   LDS: sAT 64x68 (17.4K) + sG 4x64x20 (20.5K) = 37.9 KB, 2 blocks/CU.
// ws: [0,256) maxm; [256,+2MB) c; [+2MB,+6MB) h[2][1024][512] f32;
//     [+6MB,...) z f32 [2][1024][520]. Total ~10.5 MB.
// ============================================================================

typedef unsigned short U16;
typedef __attribute__((ext_vector_type(4))) float f32x4;
typedef __attribute__((ext_vector_type(2))) float f32x2;

#define DEV __device__ __forceinline__

DEV float sigf(float x) { return 1.0f / (1.0f + expf(-x)); }

// ============================ per-step LSTM =================================
// grid 512 = 16 mtile x 32 ntile; block 256 = 4 waves.
// wave w == gate w; lane == local row; 16 cols/lane in acc[16].
__global__ void __launch_bounds__(256, 2)
lstm_step_valu(const float* __restrict__ x, const float* __restrict__ a,
               const float* __restrict__ w_ih, const float* __restrict__ w_hh,
               const float* __restrict__ b_ih, const float* __restrict__ b_hh,
               const float* __restrict__ h_in, float* __restrict__ h_out,
               float* __restrict__ c_ws, const float* __restrict__ maxm_p,
               int s) {
  __shared__ float sAT[64 * 68];        // [row][k]: 64 rows x 64 k, pad 68
  __shared__ float sG[4][64 * 20];      // [gate][row][jj 0..15], pad 20

  const int tid = threadIdx.x;
  const int lane = tid & 63;            // local row
  const int wid = __builtin_amdgcn_readfirstlane(tid >> 6);  // gate, SGPR
  const int bid = blockIdx.x;
  const int ntile = bid & 31, mtile = bid >> 5;
  const int m0 = mtile * 64, j0 = ntile * 16;
  const int ngbase = wid * 512 + j0;    // weight row of col c: ngbase + c

  float acc[16];
#pragma unroll
  for (int c = 0; c < 16; c++) acc[c] = 0.f;

  const float ts = (float)s / (*maxm_p);
  const int nch = (s == 0) ? 1 : 9;     // h == 0 at s == 0

  for (int ch = 0; ch < nch; ch++) {
    // ---- stage A chunk row-major: sAT[row][k] ----
    if (ch == 0) {                      // x_in: 0..47 x, 48..62 a, 63 t
      size_t srow = (size_t)(199 - s) * 1024 + (size_t)m0;
      for (int idx = tid; idx < 4096; idx += 256) {
        int row = idx >> 6, k = idx & 63;
        float v;
        if (k < 48)      v = x[(srow + row) * 48 + k];
        else if (k < 63) v = a[(srow + row) * 15 + (k - 48)];
        else             v = ts;        // exact fp32, same as reference
        sAT[row * 68 + k] = v;
      }
    } else {
      int k0 = (ch - 1) * 64;
      for (int idx = tid; idx < 1024; idx += 256) {
        int row = idx >> 4, kq = (idx & 15) * 4;
        *(f32x4*)&sAT[row * 68 + kq] =
            *(const f32x4*)&h_in[(size_t)(m0 + row) * 512 + k0 + kq];
      }
    }
    __syncthreads();

    // wave-uniform weight base for this chunk
    const float* wb;
    int wstride;
    if (ch == 0) { wb = w_ih + (size_t)ngbase * 64;                  wstride = 64;  }
    else         { wb = w_hh + (size_t)ngbase * 512 + (ch - 1) * 64; wstride = 512; }

    const float* aRow = &sAT[lane * 68];
    f32x4 av = *(const f32x4*)aRow;     // k4 = 0, software-pipelined
#pragma unroll
    for (int k4 = 0; k4 < 16; k4++) {
      f32x4 avn;
      if (k4 < 15) avn = *(const f32x4*)(aRow + (k4 + 1) * 4);
#pragma unroll
      for (int c = 0; c < 16; c++) {
        // wave-uniform address -> s_load; SGPR operand to v_fmac
        f32x4 wv = *(const f32x4*)(wb + (size_t)c * wstride + k4 * 4);
        acc[c] += av[0] * wv[0] + av[1] * wv[1] + av[2] * wv[2] + av[3] * wv[3];
      }
      av = avn;
    }
    __syncthreads();
  }

  // ---- gates (+bias) -> LDS ----
#pragma unroll
  for (int c = 0; c < 16; c++) {
    int ng = ngbase + c;
    float bias = b_ih[ng] + b_hh[ng];   // wave-uniform scalar
    sG[wid][lane * 20 + c] = acc[c] + bias;
  }
  __syncthreads();

  // ---- elementwise cell: 4 elems/thread; c,h fp32 in ws ----
  {
    int m = tid >> 2, jq = (tid & 3) * 4;
    size_t base = (size_t)(m0 + m) * 512 + j0 + jq;
    f32x4 cv = {0.f, 0.f, 0.f, 0.f};
    if (s > 0) cv = *(const f32x4*)&c_ws[base];
    f32x4 ncv, hv;
#pragma unroll
    for (int u = 0; u < 4; u++) {
      int jj = jq + u;
      float gi = sG[0][m * 20 + jj];
      float gf = sG[1][m * 20 + jj];
      float gg = sG[2][m * 20 + jj];
      float go = sG[3][m * 20 + jj];
      float c = sigf(gf) * cv[u] + sigf(gi) * tanhf(gg);
      ncv[u] = c;
      hv[u] = sigf(go) * tanhf(c);
    }
    *(f32x4*)&c_ws[base] = ncv;
    *(f32x4*)&h_out[base] = hv;
  }
}

// ============================= max(m) =======================================
__global__ void __launch_bounds__(1024)
maxm_kernel(const float* __restrict__ mv, float* __restrict__ out) {
  __shared__ float red[1024];
  int tid = threadIdx.x;
  float mx = -3.0e38f;
  for (int i = tid; i < 200 * 1024; i += 1024) mx = fmaxf(mx, mv[i]);
  red[tid] = mx;
  __syncthreads();
  for (int s = 512; s > 0; s >>= 1) {
    if (tid < s) red[tid] = fmaxf(red[tid], red[tid + s]);
    __syncthreads();
  }
  if (tid == 0) *out = red[0];
}

// ============ head layer 1: z = tanh(h @ {lw1,vw1}^T + b1) ==================
__global__ void __launch_bounds__(256, 2)
head1_valu(const float* __restrict__ h, const float* __restrict__ lw1,
           const float* __restrict__ lb1, const float* __restrict__ vw1,
           const float* __restrict__ vb1, float* __restrict__ z) {
  __shared__ float sAT[64 * 68];        // [k][row]: 64 k x 64 rows, pad 68
  const int tid = threadIdx.x;
  const int rg = tid & 15;              // rows rg*4..+3
  const int cgrp = tid >> 4;            // cols n0+cgrp*4..+3
  const int bid = blockIdx.x;
  const int mt = bid & 15, nt = bid >> 4;
  const int m0 = mt * 64;
  const int nb = nt * 64 + cgrp * 4;

  const float* wr[4];
  float bias[4];
  int hdv[4], wnv[4], valid[4];
#pragma unroll
  for (int c = 0; c < 4; c++) {
    int n = nb + c;
    valid[c] = (n < 1026);
    int hd = valid[c] ? (n >= 513) : 0;
    int wn = valid[c] ? (n - hd * 513) : 0;
    hdv[c] = hd; wnv[c] = wn;
    wr[c] = (hd ? vw1 : lw1) + (size_t)wn * 512;
    bias[c] = valid[c] ? (hd ? vb1[wn] : lb1[wn]) : 0.f;
  }

  float acc[4][4];
#pragma unroll
  for (int i = 0; i < 4; i++)
#pragma unroll
    for (int c = 0; c < 4; c++) acc[i][c] = 0.f;

  for (int ch = 0; ch < 8; ch++) {
    int k0 = ch * 64;
    for (int idx = tid; idx < 4096; idx += 256) {
      int row = idx >> 6, k = idx & 63;
      sAT[k * 68 + row] = h[(size_t)(m0 + row) * 512 + k0 + k];
    }
    __syncthreads();
#pragma unroll 4
    for (int k4 = 0; k4 < 16; k4++) {
      f32x4 wv[4];
#pragma unroll
      for (int c = 0; c < 4; c++)
        wv[c] = *(const f32x4*)(wr[c] + k0 + k4 * 4);
      f32x4 rv[4];
#pragma unroll
      for (int kk = 0; kk < 4; kk++)
        rv[kk] = *(const f32x4*)&sAT[(k4 * 4 + kk) * 68 + rg * 4];
#pragma unroll
      for (int kk = 0; kk < 4; kk++)
#pragma unroll
        for (int c = 0; c < 4; c++) {
          acc[0][c] += rv[kk][0] * wv[c][kk];
          acc[1][c] += rv[kk][1] * wv[c][kk];
          acc[2][c] += rv[kk][2] * wv[c][kk];
          acc[3][c] += rv[kk][3] * wv[c][kk];
        }
    }
    __syncthreads();
  }
#pragma unroll
  for (int c = 0; c < 4; c++) {
    if (!valid[c]) continue;
#pragma unroll
    for (int i = 0; i < 4; i++) {
      int m = m0 + rg * 4 + i;
      z[(size_t)hdv[c] * 1024 * 520 + (size_t)m * 520 + wnv[c]] =
          tanhf(acc[i][c] + bias[c]);
    }
  }
}

// ============ head layer 2: out = tanh(z @ {lw2,vw2}^T + b2) ================
// OUTPUT IS FLOAT32: out[hd*32768 + m*32 + n].
__global__ void __launch_bounds__(256)
head2_valu(const float* __restrict__ z, const float* __restrict__ lw2,
           const float* __restrict__ lb2, const float* __restrict__ vw2,
           const float* __restrict__ vb2, float* __restrict__ out) {
  __shared__ float sZ[8 * 133];
  __shared__ float sW[32 * 133];
  const int tid = threadIdx.x;
  const int bid = blockIdx.x;           // 0..255
  const int gr0 = bid * 8;              // rows of the 2048 concat rows
  const int hd = gr0 >> 10;
  const int b0 = gr0 & 1023;
  const float* w2 = hd ? vw2 : lw2;
  const float* b2 = hd ? vb2 : lb2;
  const float* zh = z + (size_t)hd * 1024 * 520;
  const int rloc = tid >> 5, col = tid & 31;
  float acc = 0.f;

  for (int ch = 0; ch < 5; ch++) {
    int kc = ch * 128;
    for (int idx = tid; idx < 1024; idx += 256) {
      int row = idx >> 7, k = idx & 127;
      int kk = kc + k;
      sZ[row * 133 + k] = (kk < 513) ? zh[(size_t)(b0 + row) * 520 + kk] : 0.f;
    }
    for (int idx = tid; idx < 4096; idx += 256) {
      int row = idx >> 7, k = idx & 127;
      int kk = kc + k;
      sW[row * 133 + k] = (kk < 513) ? w2[(size_t)row * 513 + kk] : 0.f;
    }
    __syncthreads();
#pragma unroll 8
    for (int k = 0; k < 128; k++)
      acc += sZ[rloc * 133 + k] * sW[col * 133 + k];
    __syncthreads();
  }
  out[(size_t)hd * 32768 + (size_t)(b0 + rloc) * 32 + col] = tanhf(acc + b2[col]);
}

// ============================================================================
extern "C" void kernel_launch(void* const* d_in, const int* in_sizes, int n_in,
                              void* d_out, int out_size, void* d_ws, size_t ws_size,
                              hipStream_t stream) {
  (void)in_sizes; (void)n_in; (void)out_size; (void)ws_size;
  const float* x    = (const float*)d_in[0];
  const float* a    = (const float*)d_in[1];
  const float* mm   = (const float*)d_in[2];
  const float* w_ih = (const float*)d_in[3];
  const float* w_hh = (const float*)d_in[4];
  const float* b_ih = (const float*)d_in[5];
  const float* b_hh = (const float*)d_in[6];
  const float* lw1  = (const float*)d_in[7];
  const float* lb1  = (const float*)d_in[8];
  const float* lw2  = (const float*)d_in[9];
  const float* lb2  = (const float*)d_in[10];
  const float* vw1  = (const float*)d_in[11];
  const float* vb1  = (const float*)d_in[12];
  const float* vw2  = (const float*)d_in[13];
  const float* vb2  = (const float*)d_in[14];

  char* wsb = (char*)d_ws;
  float* maxm = (float*)wsb;                                   // 256 B
  float* c_ws = (float*)(wsb + 256);                           // 2 MB
  float* hbuf = (float*)(wsb + 256 + 1024 * 512 * 4);          // 2 x 2 MB
  float* z    = (float*)(wsb + 256 + 3 * 1024 * 512 * 4);      // 2x1024x520 f32

  maxm_kernel<<<1, 1024, 0, stream>>>(mm, maxm);
  for (int s = 0; s < 200; s++) {
    const float* h_in = hbuf + (size_t)(s & 1) * 1024 * 512;
    float* h_out = hbuf + (size_t)((s & 1) ^ 1) * 1024 * 512;
    lstm_step_valu<<<512, 256, 0, stream>>>(x, a, w_ih, w_hh, b_ih, b_hh,
                                            h_in, h_out, c_ws, maxm, s);
  }
  // s=199 wrote hbuf[0]
  head1_valu<<<272, 256, 0, stream>>>(hbuf, lw1, lb1, vw1, vb1, z);
  head2_valu<<<256, 256, 0, stream>>>(z, lw2, lb2, vw2, vb2, (float*)d_out);
}

// Round 3
// 5482.195 us; speedup vs baseline: 6.6922x; 6.6922x over previous
//
#include <hip/hip_runtime.h>
#include <cstdint>

// ============================================================================
// EncoderLSTMReal: reverse LSTM (T=200,B=1024,H=512,IN=64) + 2 tanh-MLP heads.
// CONTRACT (established R0-R8):
//   - inputs fp32, dict order (R6 NaN kills bf16-input; R5 permutation test)
//   - OUTPUT FLOAT32; mu = out[0..32768), logvar next
//   - h kept fp32 in ws (heads unchanged)
// Round-12 (R3): split-fp16 MFMA GEMM for the LSTM step.
//   R2 post-mortem: compiler does NOT scalarize uniform weight loads -> VMEM
//   latency-bound (220 us). R1's VALU path floors at ~50 us structurally.
//   New: D = Ah*Bh + Al*Bh + Ah*Bl via mfma_f32_16x16x32_f16, fp32 acc.
//   Error ~2^-22/product < fp32-reorder noise already tolerated.
//   Weights hi/lo pre-split once (wprep) into ws; h split at stage time.
//   LDS in fragment order (reads = ds_read_b128 at lane*16, conflict-free),
//   double-buffered, register-prefetch issued before MFMA phase.
// ws: [0,256) maxm; [256,+2MB) c; [+2MB,+6MB) h[2][1024][512] f32;
//     [+6MB,+10.26MB) z f32 [2][1024][520]; then whi/wlo f16 [2048][576].
// ============================================================================

typedef _Float16 f16;
typedef __attribute__((ext_vector_type(8))) _Float16 f16x8;
typedef __attribute__((ext_vector_type(4))) float f32x4;

#define DEV __device__ __forceinline__

DEV float sigf(float x) { return 1.0f / (1.0f + expf(-x)); }

// =================== weight split prep: [2048][576] hi/lo ===================
__global__ void __launch_bounds__(256)
wprep_kernel(const float* __restrict__ w_ih, const float* __restrict__ w_hh,
             f16* __restrict__ whi, f16* __restrict__ wlo) {
  int idx = blockIdx.x * 256 + threadIdx.x;   // over 2048*576
  if (idx >= 2048 * 576) return;
  int n = idx / 576, k = idx - n * 576;
  float v = (k < 64) ? w_ih[n * 64 + k] : w_hh[(size_t)n * 512 + (k - 64)];
  f16 h = (f16)v;
  whi[idx] = h;
  wlo[idx] = (f16)(v - (float)h);
}

// ============================ per-step LSTM =================================
// grid 256 = 16 mtile x 16 ntile; block 256 = 4 waves (2x2 wave tiles).
// Block tile: 64 rows x 128 cols, cols = 4 gates x 32 jj (jj-block = nt*32).
// K = 576 = 9 chunks of 64 (2 ksteps of 32 each).
// LDS frag-order: line(rt|ct, ks, p, lane) -> 8 halves at line*16 B.
__global__ void __launch_bounds__(256)
lstm_step_mfma(const float* __restrict__ x, const float* __restrict__ a,
               const f16* __restrict__ whi, const f16* __restrict__ wlo,
               const float* __restrict__ b_ih, const float* __restrict__ b_hh,
               const float* __restrict__ h_in, float* __restrict__ h_out,
               float* __restrict__ c_ws, const float* __restrict__ maxm_p,
               int s) {
  __shared__ f16 sAB[2][24576];     // per buf: A lines [0,1024)*8h, B at +8192h
  __shared__ float sG[64 * 132];    // gates fp32, col = gate*32 + jj

  const int tid = threadIdx.x;
  const int lane = tid & 63;
  const int wid = tid >> 6;
  const int nt = blockIdx.x & 15, mt = blockIdx.x >> 4;
  const int m0 = mt * 64, j0 = nt * 32;
  const int wr = wid >> 1, wc = wid & 1;

  const float ts = (float)s / (*maxm_p);
  const int nch = (s == 0) ? 1 : 9;

  // ---- per-thread staging line decodes ----
  // A pair-lines: ids {tid, tid+256} of 512 (rt 0..3, ks 0..1, lane 0..63)
  int a_ln[2], a_rt[2], a_ks[2];
#pragma unroll
  for (int t2 = 0; t2 < 2; t2++) {
    int id = tid + t2 * 256;
    a_ln[t2] = id & 63; a_ks[t2] = (id >> 6) & 1; a_rt[t2] = id >> 7;
  }
  // B lines: ids {tid + i*256} of 2048 (ct 0..7, ks, p, lane)
  const f16* bsrc[8];
  int b_loff[8];                    // LDS half-offset of the line
#pragma unroll
  for (int i = 0; i < 8; i++) {
    int id = tid + i * 256;
    int ln = id & 63, p = (id >> 6) & 1, ks = (id >> 7) & 1, ct = id >> 8;
    int col = (ct >> 1) * 512 + j0 + (ct & 1) * 16 + (ln & 15);
    int kl = ks * 32 + (ln >> 4) * 8;
    const f16* plane = p ? wlo : whi;
    bsrc[i] = plane + (size_t)col * 576 + kl;
    b_loff[i] = 8192 + (((ct * 2 + ks) * 2 + p) * 64 + ln) * 8;
  }

  f32x4 acc[2][4];
#pragma unroll
  for (int r = 0; r < 2; r++)
#pragma unroll
    for (int c = 0; c < 4; c++) acc[r][c] = (f32x4){0.f, 0.f, 0.f, 0.f};

  // ---- prologue: stage chunk 0 into buf 0 ----
  {
#pragma unroll
    for (int i = 0; i < 8; i++) {
      f32x4 v = *(const f32x4*)(bsrc[i]);            // chunk 0
      *(f32x4*)&sAB[0][b_loff[i]] = v;
    }
    size_t srow = (size_t)(199 - s) * 1024 + m0;
#pragma unroll
    for (int t2 = 0; t2 < 2; t2++) {
      int ln = a_ln[t2], ks = a_ks[t2], rt = a_rt[t2];
      int row = rt * 16 + (ln & 15);
      int kb = ks * 32 + (ln >> 4) * 8;
      f16x8 hi, lo;
#pragma unroll
      for (int e = 0; e < 8; e++) {
        int k = kb + e;
        float vv;
        if (k < 48)      vv = x[(srow + row) * 48 + k];
        else if (k < 63) vv = a[(srow + row) * 15 + (k - 48)];
        else             vv = ts;
        f16 h8 = (f16)vv;
        hi[e] = h8; lo[e] = (f16)(vv - (float)h8);
      }
      int lbase = ((rt * 2 + ks) * 2 + 0) * 64 + ln;
      *(f16x8*)&sAB[0][lbase * 8] = hi;
      *(f16x8*)&sAB[0][(lbase + 64) * 8] = lo;       // p=1 line = +64
    }
  }
  __syncthreads();

  // ---- main loop: prefetch ch+1 to regs, MFMA on cur, write buf^1 ----
  int cur = 0;
  for (int ch = 0; ch < nch; ch++) {
    f32x4 pb[8]; f32x4 pa[4];
    const bool pref = (ch + 1 < nch);
    if (pref) {
      int kg = (ch + 1) * 64;
#pragma unroll
      for (int i = 0; i < 8; i++)
        pb[i] = *(const f32x4*)(bsrc[i] + kg);
      int kh = ch * 64;                              // h chunk (ch+1)-1
#pragma unroll
      for (int t2 = 0; t2 < 2; t2++) {
        int ln = a_ln[t2], ks = a_ks[t2], rt = a_rt[t2];
        int row = m0 + rt * 16 + (ln & 15);
        int kk = kh + ks * 32 + (ln >> 4) * 8;
        pa[t2 * 2 + 0] = *(const f32x4*)&h_in[(size_t)row * 512 + kk];
        pa[t2 * 2 + 1] = *(const f32x4*)&h_in[(size_t)row * 512 + kk + 4];
      }
    }

    const f16* buf = sAB[cur];
#pragma unroll
    for (int ks = 0; ks < 2; ks++) {
      f16x8 Af[2][2], Bf[4][2];
#pragma unroll
      for (int r2 = 0; r2 < 2; r2++) {
        int rt = wr * 2 + r2;
#pragma unroll
        for (int p = 0; p < 2; p++)
          Af[r2][p] = *(const f16x8*)&buf[(((rt * 2 + ks) * 2 + p) * 64 + lane) * 8];
      }
#pragma unroll
      for (int c4 = 0; c4 < 4; c4++) {
        int ct = wc * 4 + c4;
#pragma unroll
        for (int p = 0; p < 2; p++)
          Bf[c4][p] = *(const f16x8*)&buf[8192 + (((ct * 2 + ks) * 2 + p) * 64 + lane) * 8];
      }
      // hi*hi (8 independent), then lo*hi, then hi*lo
#pragma unroll
      for (int c4 = 0; c4 < 4; c4++)
#pragma unroll
        for (int r2 = 0; r2 < 2; r2++)
          acc[r2][c4] = __builtin_amdgcn_mfma_f32_16x16x32_f16(
              Af[r2][0], Bf[c4][0], acc[r2][c4], 0, 0, 0);
#pragma unroll
      for (int c4 = 0; c4 < 4; c4++)
#pragma unroll
        for (int r2 = 0; r2 < 2; r2++)
          acc[r2][c4] = __builtin_amdgcn_mfma_f32_16x16x32_f16(
              Af[r2][1], Bf[c4][0], acc[r2][c4], 0, 0, 0);
#pragma unroll
      for (int c4 = 0; c4 < 4; c4++)
#pragma unroll
        for (int r2 = 0; r2 < 2; r2++)
          acc[r2][c4] = __builtin_amdgcn_mfma_f32_16x16x32_f16(
              Af[r2][0], Bf[c4][1], acc[r2][c4], 0, 0, 0);
    }

    if (pref) {
      f16* nb = sAB[cur ^ 1];
#pragma unroll
      for (int i = 0; i < 8; i++)
        *(f32x4*)&nb[b_loff[i]] = pb[i];
#pragma unroll
      for (int t2 = 0; t2 < 2; t2++) {
        int ln = a_ln[t2], ks = a_ks[t2], rt = a_rt[t2];
        float v[8];
        *(f32x4*)&v[0] = pa[t2 * 2 + 0];
        *(f32x4*)&v[4] = pa[t2 * 2 + 1];
        f16x8 hi, lo;
#pragma unroll
        for (int e = 0; e < 8; e++) {
          f16 h8 = (f16)v[e];
          hi[e] = h8; lo[e] = (f16)(v[e] - (float)h8);
        }
        int lbase = ((rt * 2 + ks) * 2 + 0) * 64 + ln;
        *(f16x8*)&nb[lbase * 8] = hi;
        *(f16x8*)&nb[(lbase + 64) * 8] = lo;
      }
    }
    __syncthreads();
    cur ^= 1;
  }

  // ---- acc -> sG (C/D: col=lane&15, row=(lane>>4)*4+reg; m89-verified) ----
#pragma unroll
  for (int r2 = 0; r2 < 2; r2++) {
    int rowb = wr * 32 + r2 * 16 + (lane >> 4) * 4;
#pragma unroll
    for (int c4 = 0; c4 < 4; c4++) {
      int colb = wc * 64 + c4 * 16 + (lane & 15);
#pragma unroll
      for (int i = 0; i < 4; i++)
        sG[(rowb + i) * 132 + colb] = acc[r2][c4][i];
    }
  }
  __syncthreads();

  // ---- elementwise cell: 8 elems/thread; c,h fp32 in ws ----
  {
    int m = tid >> 2, jq = (tid & 3) * 8;
    size_t base = (size_t)(m0 + m) * 512 + j0 + jq;
    float cvv[8];
    if (s > 0) {
      *(f32x4*)&cvv[0] = *(const f32x4*)&c_ws[base];
      *(f32x4*)&cvv[4] = *(const f32x4*)&c_ws[base + 4];
    } else {
#pragma unroll
      for (int u = 0; u < 8; u++) cvv[u] = 0.f;
    }
    float nc[8], nh[8];
#pragma unroll
    for (int u = 0; u < 8; u++) {
      int j = jq + u;
      int n0 = j0 + j;
      float gi = sG[m * 132 +      j] + b_ih[n0]        + b_hh[n0];
      float gf = sG[m * 132 + 32 + j] + b_ih[512 + n0]  + b_hh[512 + n0];
      float gg = sG[m * 132 + 64 + j] + b_ih[1024 + n0] + b_hh[1024 + n0];
      float go = sG[m * 132 + 96 + j] + b_ih[1536 + n0] + b_hh[1536 + n0];
      float c = sigf(gf) * cvv[u] + sigf(gi) * tanhf(gg);
      nc[u] = c;
      nh[u] = sigf(go) * tanhf(c);
    }
    *(f32x4*)&c_ws[base]     = *(f32x4*)&nc[0];
    *(f32x4*)&c_ws[base + 4] = *(f32x4*)&nc[4];
    *(f32x4*)&h_out[base]     = *(f32x4*)&nh[0];
    *(f32x4*)&h_out[base + 4] = *(f32x4*)&nh[4];
  }
}

// ============================= max(m) =======================================
__global__ void __launch_bounds__(1024)
maxm_kernel(const float* __restrict__ mv, float* __restrict__ out) {
  __shared__ float red[1024];
  int tid = threadIdx.x;
  float mx = -3.0e38f;
  for (int i = tid; i < 200 * 1024; i += 1024) mx = fmaxf(mx, mv[i]);
  red[tid] = mx;
  __syncthreads();
  for (int s = 512; s > 0; s >>= 1) {
    if (tid < s) red[tid] = fmaxf(red[tid], red[tid + s]);
    __syncthreads();
  }
  if (tid == 0) *out = red[0];
}

// ============ head layer 1: z = tanh(h @ {lw1,vw1}^T + b1) ==================
__global__ void __launch_bounds__(256, 2)
head1_valu(const float* __restrict__ h, const float* __restrict__ lw1,
           const float* __restrict__ lb1, const float* __restrict__ vw1,
           const float* __restrict__ vb1, float* __restrict__ z) {
  __shared__ float sAT[64 * 68];
  const int tid = threadIdx.x;
  const int rg = tid & 15;
  const int cgrp = tid >> 4;
  const int bid = blockIdx.x;
  const int mt = bid & 15, nt = bid >> 4;
  const int m0 = mt * 64;
  const int nb = nt * 64 + cgrp * 4;

  const float* wr[4];
  float bias[4];
  int hdv[4], wnv[4], valid[4];
#pragma unroll
  for (int c = 0; c < 4; c++) {
    int n = nb + c;
    valid[c] = (n < 1026);
    int hd = valid[c] ? (n >= 513) : 0;
    int wn = valid[c] ? (n - hd * 513) : 0;
    hdv[c] = hd; wnv[c] = wn;
    wr[c] = (hd ? vw1 : lw1) + (size_t)wn * 512;
    bias[c] = valid[c] ? (hd ? vb1[wn] : lb1[wn]) : 0.f;
  }

  float acc[4][4];
#pragma unroll
  for (int i = 0; i < 4; i++)
#pragma unroll
    for (int c = 0; c < 4; c++) acc[i][c] = 0.f;

  for (int ch = 0; ch < 8; ch++) {
    int k0 = ch * 64;
    for (int idx = tid; idx < 4096; idx += 256) {
      int row = idx >> 6, k = idx & 63;
      sAT[k * 68 + row] = h[(size_t)(m0 + row) * 512 + k0 + k];
    }
    __syncthreads();
#pragma unroll 4
    for (int k4 = 0; k4 < 16; k4++) {
      f32x4 wv[4];
#pragma unroll
      for (int c = 0; c < 4; c++)
        wv[c] = *(const f32x4*)(wr[c] + k0 + k4 * 4);
      f32x4 rv[4];
#pragma unroll
      for (int kk = 0; kk < 4; kk++)
        rv[kk] = *(const f32x4*)&sAT[(k4 * 4 + kk) * 68 + rg * 4];
#pragma unroll
      for (int kk = 0; kk < 4; kk++)
#pragma unroll
        for (int c = 0; c < 4; c++) {
          acc[0][c] += rv[kk][0] * wv[c][kk];
          acc[1][c] += rv[kk][1] * wv[c][kk];
          acc[2][c] += rv[kk][2] * wv[c][kk];
          acc[3][c] += rv[kk][3] * wv[c][kk];
        }
    }
    __syncthreads();
  }
#pragma unroll
  for (int c = 0; c < 4; c++) {
    if (!valid[c]) continue;
#pragma unroll
    for (int i = 0; i < 4; i++) {
      int m = m0 + rg * 4 + i;
      z[(size_t)hdv[c] * 1024 * 520 + (size_t)m * 520 + wnv[c]] =
          tanhf(acc[i][c] + bias[c]);
    }
  }
}

// ============ head layer 2: out = tanh(z @ {lw2,vw2}^T + b2) ================
__global__ void __launch_bounds__(256)
head2_valu(const float* __restrict__ z, const float* __restrict__ lw2,
           const float* __restrict__ lb2, const float* __restrict__ vw2,
           const float* __restrict__ vb2, float* __restrict__ out) {
  __shared__ float sZ[8 * 133];
  __shared__ float sW[32 * 133];
  const int tid = threadIdx.x;
  const int bid = blockIdx.x;
  const int gr0 = bid * 8;
  const int hd = gr0 >> 10;
  const int b0 = gr0 & 1023;
  const float* w2 = hd ? vw2 : lw2;
  const float* b2 = hd ? vb2 : lb2;
  const float* zh = z + (size_t)hd * 1024 * 520;
  const int rloc = tid >> 5, col = tid & 31;
  float acc = 0.f;

  for (int ch = 0; ch < 5; ch++) {
    int kc = ch * 128;
    for (int idx = tid; idx < 1024; idx += 256) {
      int row = idx >> 7, k = idx & 127;
      int kk = kc + k;
      sZ[row * 133 + k] = (kk < 513) ? zh[(size_t)(b0 + row) * 520 + kk] : 0.f;
    }
    for (int idx = tid; idx < 4096; idx += 256) {
      int row = idx >> 7, k = idx & 127;
      int kk = kc + k;
      sW[row * 133 + k] = (kk < 513) ? w2[(size_t)row * 513 + kk] : 0.f;
    }
    __syncthreads();
#pragma unroll 8
    for (int k = 0; k < 128; k++)
      acc += sZ[rloc * 133 + k] * sW[col * 133 + k];
    __syncthreads();
  }
  out[(size_t)hd * 32768 + (size_t)(b0 + rloc) * 32 + col] = tanhf(acc + b2[col]);
}

// ============================================================================
extern "C" void kernel_launch(void* const* d_in, const int* in_sizes, int n_in,
                              void* d_out, int out_size, void* d_ws, size_t ws_size,
                              hipStream_t stream) {
  (void)in_sizes; (void)n_in; (void)out_size; (void)ws_size;
  const float* x    = (const float*)d_in[0];
  const float* a    = (const float*)d_in[1];
  const float* mm   = (const float*)d_in[2];
  const float* w_ih = (const float*)d_in[3];
  const float* w_hh = (const float*)d_in[4];
  const float* b_ih = (const float*)d_in[5];
  const float* b_hh = (const float*)d_in[6];
  const float* lw1  = (const float*)d_in[7];
  const float* lb1  = (const float*)d_in[8];
  const float* lw2  = (const float*)d_in[9];
  const float* lb2  = (const float*)d_in[10];
  const float* vw1  = (const float*)d_in[11];
  const float* vb1  = (const float*)d_in[12];
  const float* vw2  = (const float*)d_in[13];
  const float* vb2  = (const float*)d_in[14];

  char* wsb = (char*)d_ws;
  float* maxm = (float*)wsb;                                   // 256 B
  float* c_ws = (float*)(wsb + 256);                           // 2 MB
  float* hbuf = (float*)(wsb + 256 + 1024 * 512 * 4);          // 2 x 2 MB
  float* z    = (float*)(wsb + 256 + 3 * 1024 * 512 * 4);      // 2x1024x520 f32
  f16*   whi  = (f16*)(wsb + 10551552);                        // 2048*576 f16
  f16*   wlo  = (f16*)(wsb + 12910848);                        // 2048*576 f16

  maxm_kernel<<<1, 1024, 0, stream>>>(mm, maxm);
  wprep_kernel<<<4608, 256, 0, stream>>>(w_ih, w_hh, whi, wlo);
  for (int s = 0; s < 200; s++) {
    const float* h_in = hbuf + (size_t)(s & 1) * 1024 * 512;
    float* h_out = hbuf + (size_t)((s & 1) ^ 1) * 1024 * 512;
    lstm_step_mfma<<<256, 256, 0, stream>>>(x, a, whi, wlo, b_ih, b_hh,
                                            h_in, h_out, c_ws, maxm, s);
  }
  // s=199 wrote hbuf[0]
  head1_valu<<<272, 256, 0, stream>>>(hbuf, lw1, lb1, vw1, vb1, z);
  head2_valu<<<256, 256, 0, stream>>>(z, lw2, lb2, vw2, vb2, (float*)d_out);
}